// Round 3
// baseline (733.724 us; speedup 1.0000x reference)
//
#include <hip/hip_runtime.h>
#include <stdint.h>

// GenerativeWorldModel: B=2048,T=50,N=23,F=4,H=64,FUT=10. All I/O fp32.
// 1 wave = 1 batch, 512 thr/block (8 waves), 256 blocks, no barriers in loop.
// All GEMMs transposed (D[row=feature][col=node]); h recurrence in registers.
// R3 vs baseline (343us/dispatch):
//  1) cvt_tile via two-arg v_permlane32_swap: swap(u0,u2) returns
//     {word0, word2} of the B-frag directly (r0={lo.u0, lo.u2 into hi lanes},
//     r1={hi.u0 into lo lanes, hi.u2}) -- 4 VALU permlanes replace 4
//     ds_bpermute + cndmasks. (R1 had the lane mapping wrong: words mix
//     BOTH halves' registers; fixed per baseline shuffle derivation.)
//  2) adj LDS staging (div-23 transpose + ds round trip) -> direct per-row
//     global loads into registers; bA frags packed straight from regs.
//  3) software pipeline: S-path(t+1) (x/adj -> E -> S) is h-independent, so
//     it runs between GRU-MFMA(t) and the trans-heavy activations of t.

typedef _Float16 f16;
typedef f16   f16x2  __attribute__((ext_vector_type(2)));
typedef f16   f16x8  __attribute__((ext_vector_type(8)));
typedef float f32x4n __attribute__((ext_vector_type(4)));
typedef float f32x16 __attribute__((ext_vector_type(16)));
typedef int   i32x2  __attribute__((ext_vector_type(2)));
typedef float f32x4u __attribute__((ext_vector_type(4), aligned(4)));

#define WBYTES 69632            // 68 weight frags * 1024 B
#define PW 512                  // per-wave: xL f32[128]
#define SMEM_BYTES (WBYTES + 8 * PW)   // 73728

static __device__ __forceinline__ unsigned pk2(float a, float b) {
    f16x2 h; h[0] = (f16)a; h[1] = (f16)b;
    return __builtin_bit_cast(unsigned, h);
}
static __device__ __forceinline__ f16x8 mkfrag(unsigned a, unsigned b, unsigned c, unsigned d) {
    uint4 u = make_uint4(a, b, c, d);
    return __builtin_bit_cast(f16x8, u);
}
// v_permlane32_swap(a,b): exchanges hi-half(a) with lo-half(b).
// r0 = {a.lo | b.lo-values in hi lanes}, r1 = {a.hi-values in lo lanes | b.hi}
static __device__ __forceinline__ void pswap2(unsigned a, unsigned b,
                                              unsigned& r0, unsigned& r1) {
    auto r = __builtin_amdgcn_permlane32_swap((int)a, (int)b, false, false);
    i32x2 v = __builtin_bit_cast(i32x2, r);
    r0 = (unsigned)v[0]; r1 = (unsigned)v[1];
}
// hi-dup of x: every lane gets x from lane 32|(l&31)  (valid for lo lanes)
static __device__ __forceinline__ unsigned dup_hi(unsigned x) {
    unsigned r0, r1; pswap2(x, x, r0, r1); return r1;
}

static __device__ __forceinline__ float sigm(float x) {
    return __builtin_amdgcn_rcpf(1.f + __expf(-x));
}
static __device__ __forceinline__ float tanhp(float x) {
    return 1.f - 2.f * __builtin_amdgcn_rcpf(1.f + __expf(2.f * x));
}
// C-layout f32x16 tile (row=(i&3)+8*(i>>2)+4*hf, col=l31) -> two B-frags
// fe = tile rows 0..15, fo = rows 16..31.  Correct lane mapping:
//   fe(lo lanes) = (lo.u0, lo.u1, hi.u0, hi.u1)   [rows 0-3, 4-7]
//   fe(hi lanes) = (lo.u2, lo.u3, hi.u2, hi.u3)   [rows 8-11, 12-15]
// pswap2(u0,u2) yields exactly (word0, word2); pswap2(u1,u3) -> (word1, word3).
static __device__ __forceinline__ void cvt_tile(const f32x16& v, f16x8& fe, f16x8& fo) {
    unsigned e0, e1, e2, e3, o0, o1, o2, o3;
    pswap2(pk2(v[0], v[1]),   pk2(v[4], v[5]),   e0, e2);
    pswap2(pk2(v[2], v[3]),   pk2(v[6], v[7]),   e1, e3);
    pswap2(pk2(v[8], v[9]),   pk2(v[12], v[13]), o0, o2);
    pswap2(pk2(v[10], v[11]), pk2(v[14], v[15]), o1, o3);
    fe = mkfrag(e0, e1, e2, e3);
    fo = mkfrag(o0, o1, o2, o3);
}

__global__ __launch_bounds__(512, 2) void gwm_kernel(
    const float* __restrict__ xseq, const float* __restrict__ adjseq,
    const float* __restrict__ Wg,  const float* __restrict__ bg,
    const float* __restrict__ Wih, const float* __restrict__ Whh,
    const float* __restrict__ bih, const float* __restrict__ bhh,
    const float* __restrict__ Wd1, const float* __restrict__ bd1,
    const float* __restrict__ Wd2, const float* __restrict__ bd2,
    float* __restrict__ out)
{
    extern __shared__ char smem[];
    const int tid  = threadIdx.x;
    const int lane = tid & 63;
    const int wv   = tid >> 6;
    const int l31  = lane & 31;
    const int hf   = lane >> 5;

    // ---- pack weights (A-frags, fp16) + bias columns into LDS (once) ----
    for (int idx = tid; idx < 68 * 64; idx += 512) {
        const int fi = idx >> 6, l = idx & 63, ln = l & 31, lh = l >> 5;
        float v[8];
        #pragma unroll
        for (int j = 0; j < 8; ++j) v[j] = 0.f;
        if (fi < 60) {
            const int grp = fi / 5, kt = fi - grp * 5;
            const int side = grp / 6, tau = grp - side * 6;
            const float* W = side ? Whh : Wih;
            const int row = tau * 32 + ln;
            if (kt < 4) {
                const float* s = W + row * 64 + kt * 16 + lh * 8;
                #pragma unroll
                for (int j = 0; j < 8; ++j) v[j] = s[j];
            } else if (lh == 0) {
                if (side == 0) v[0] = bih[row] + (tau < 4 ? bhh[row] : 0.f);
                else           v[0] = (tau < 4) ? 0.f : bhh[row];
            }
        } else if (fi < 65) {
            const int kt = fi - 60;
            if (kt < 4) {
                const float* s = Wd1 + ln * 64 + kt * 16 + lh * 8;
                #pragma unroll
                for (int j = 0; j < 8; ++j) v[j] = s[j];
            } else if (lh == 0) v[0] = bd1[ln];
        } else {
            const int kt = fi - 65;
            if (kt < 2) {
                if (ln < 4) {
                    const float* s = Wd2 + ln * 32 + kt * 16 + lh * 8;
                    #pragma unroll
                    for (int j = 0; j < 8; ++j) v[j] = s[j];
                }
            } else if (lh == 0 && ln < 4) v[0] = bd2[ln];
        }
        f16x8 h8;
        #pragma unroll
        for (int j = 0; j < 8; ++j) h8[j] = (f16)v[j];
        *(f16x8*)(smem + fi * 1024 + l * 16) = h8;
    }

    float* xL = (float*)(smem + WBYTES + wv * PW);   // f32[128] (92 real + zero pad)
    xL[lane] = 0.f; xL[lane + 64] = 0.f;
    __syncthreads();   // weight frags visible

    // ---- per-lane constants ----
    const f16x8 bC = (hf == 0) ? mkfrag(pk2(1.f, 0.f), 0u, 0u, 0u)
                               : mkfrag(0u, 0u, 0u, 0u);
    f16x8 aWg0, aWg1;
    {
        const int c0 = l31, c1 = 32 + l31;
        aWg0 = hf ? mkfrag(0u,0u,0u,0u)
                  : mkfrag(pk2(Wg[c0*4], Wg[c0*4+1]), pk2(Wg[c0*4+2], Wg[c0*4+3]),
                           pk2(bg[c0], 0.f), 0u);
        aWg1 = hf ? mkfrag(0u,0u,0u,0u)
                  : mkfrag(pk2(Wg[c1*4], Wg[c1*4+1]), pk2(Wg[c1*4+2], Wg[c1*4+3]),
                           pk2(bg[c1], 0.f), 0u);
    }

    const int b = blockIdx.x * 8 + wv;
    const float* xg = xseq   + (size_t)b * (50 * 92);
    const float* ag = adjseq + (size_t)b * (50 * 529);
    float* outb = out + (size_t)b * 920;

    // ---- recurrent state ----
    f32x16 hC0, hC1;
    f16x8  bH[4];
    f16x8  bS[4];
    f16x8  bA0, bA1;       // adj^T B-frags for the t currently in the S-path
    float  c[16];          // adj row prefetch: lane needs row l31 cols [8hf,8hf+8)+[16+8hf,...)
    f32x4n pfx;
    #pragma unroll
    for (int i = 0; i < 16; ++i) { hC0[i] = 0.f; hC1[i] = 0.f; }
    #pragma unroll
    for (int kt = 0; kt < 4; ++kt) bH[kt] = mkfrag(0u, 0u, 0u, 0u);

    f32x16 z16;
    #pragma unroll
    for (int i = 0; i < 16; ++i) z16[i] = 0.f;

    auto mm = [&](f32x16 acc, int fi, f16x8 bfr) -> f32x16 {
        const f16x8 aW = *(const f16x8*)(smem + fi * 1024 + lane * 16);
        return __builtin_amdgcn_mfma_f32_32x32x16_f16(aW, bfr, acc, 0, 0, 0);
    };

    // direct global->reg adj row load (replaces LDS staging + div-23 transpose)
    auto load_adj = [&](int t) {
        #pragma unroll
        for (int i = 0; i < 16; ++i) c[i] = 0.f;
        if (l31 < 23) {
            const float* ar = ag + t * 529 + l31 * 23 + 8 * hf;
            f32x4u u0 = *(const f32x4u*)ar;
            f32x4u u1 = *(const f32x4u*)(ar + 4);
            c[0]=u0[0]; c[1]=u0[1]; c[2]=u0[2]; c[3]=u0[3];
            c[4]=u1[0]; c[5]=u1[1]; c[6]=u1[2]; c[7]=u1[3];
            if (hf == 0) {                 // cols 16..22 (col 23 stays 0)
                f32x4u u2 = *(const f32x4u*)(ar + 16);
                c[8]=u2[0]; c[9]=u2[1]; c[10]=u2[2]; c[11]=u2[3];
                c[12]=ar[20]; c[13]=ar[21]; c[14]=ar[22];
            }                              // hf==1: cols 24..31 are pad -> 0
        }
    };
    auto pack_adj = [&]() {
        bA0 = mkfrag(pk2(c[0],c[1]),  pk2(c[2],c[3]),   pk2(c[4],c[5]),   pk2(c[6],c[7]));
        bA1 = mkfrag(pk2(c[8],c[9]),  pk2(c[10],c[11]), pk2(c[12],c[13]), pk2(c[14],c[15]));
    };
    auto load_x  = [&](int t) {
        if (lane < 23) pfx = *(const f32x4n*)(xg + t * 92 + 4 * lane);
    };
    auto stage_x = [&]() {
        if (lane < 23) *(f32x4n*)(xL + 4 * lane) = pfx;
    };

    // S-path: xL + bA -> bS frags (h-independent)
    auto spath = [&](f16x8* bSo) {
        f16x8 aX0, aX1;
        {
            float v0[8], v1[8];
            #pragma unroll
            for (int j = 0; j < 8; ++j) {
                const int n0 = 8 * hf + j, n1 = 16 + 8 * hf + j;
                const float x0 = xL[n0 * 4 + (l31 & 3)];
                const float x1 = xL[n1 * 4 + (l31 & 3)];
                v0[j] = (l31 < 4) ? x0 : ((l31 == 4) ? 1.f : 0.f);
                v1[j] = (l31 < 4) ? x1 : ((l31 == 4) ? 1.f : 0.f);
            }
            aX0 = mkfrag(pk2(v0[0],v0[1]), pk2(v0[2],v0[3]), pk2(v0[4],v0[5]), pk2(v0[6],v0[7]));
            aX1 = mkfrag(pk2(v1[0],v1[1]), pk2(v1[2],v1[3]), pk2(v1[4],v1[5]), pk2(v1[6],v1[7]));
        }
        f32x16 accE = z16;
        accE = __builtin_amdgcn_mfma_f32_32x32x16_f16(aX0, bA0, accE, 0, 0, 0);
        accE = __builtin_amdgcn_mfma_f32_32x32x16_f16(aX1, bA1, accE, 0, 0, 0);
        const unsigned p01 = pk2(accE[0], accE[1]), p23 = pk2(accE[2], accE[3]);
        const unsigned p4  = dup_hi(pk2(accE[0], 0.f));   // row4 lives in hi half
        const f16x8 bE = hf ? mkfrag(0u, 0u, 0u, 0u) : mkfrag(p01, p23, p4, 0u);
        f32x16 s0 = z16, s1 = z16;
        s0 = __builtin_amdgcn_mfma_f32_32x32x16_f16(aWg0, bE, s0, 0, 0, 0);
        s1 = __builtin_amdgcn_mfma_f32_32x32x16_f16(aWg1, bE, s1, 0, 0, 0);
        #pragma unroll
        for (int i = 0; i < 16; ++i) { s0[i] = fmaxf(s0[i], 0.f); s1[i] = fmaxf(s1[i], 0.f); }
        cvt_tile(s0, bSo[0], bSo[1]);
        cvt_tile(s1, bSo[2], bSo[3]);
    };

    auto gru_mfma = [&](int hnum, f32x16& aR, f32x16& aZ, f32x16& aNi, f32x16& aNh) {
        const int tR = hnum, tZ = 2 + hnum, tN = 4 + hnum;
        aR = z16; aZ = z16; aNi = z16; aNh = z16;
        #pragma unroll
        for (int kt = 0; kt < 4; ++kt) {
            aR  = mm(aR,  (0 * 6 + tR) * 5 + kt, bS[kt]);
            aR  = mm(aR,  (1 * 6 + tR) * 5 + kt, bH[kt]);
            aZ  = mm(aZ,  (0 * 6 + tZ) * 5 + kt, bS[kt]);
            aZ  = mm(aZ,  (1 * 6 + tZ) * 5 + kt, bH[kt]);
            aNi = mm(aNi, (0 * 6 + tN) * 5 + kt, bS[kt]);
            aNh = mm(aNh, (1 * 6 + tN) * 5 + kt, bH[kt]);
        }
        aR  = mm(aR,  (0 * 6 + tR) * 5 + 4, bC);
        aZ  = mm(aZ,  (0 * 6 + tZ) * 5 + 4, bC);
        aNi = mm(aNi, (0 * 6 + tN) * 5 + 4, bC);
        aNh = mm(aNh, (1 * 6 + tN) * 5 + 4, bC);
    };
    auto act = [&](f32x16& hv, const f32x16& aR, const f32x16& aZ,
                   const f32x16& aNi, const f32x16& aNh, f16x8& nbe, f16x8& nbo) {
        #pragma unroll
        for (int i = 0; i < 16; ++i) {
            const float r = sigm(aR[i]);
            const float z = sigm(aZ[i]);
            const float n = tanhp(aNi[i] + r * aNh[i]);
            hv[i] = n + z * (hv[i] - n);
        }
        cvt_tile(hv, nbe, nbo);
    };

    // ---- prologue: S(0) + prefetch t=1 ----
    load_x(0); stage_x();
    load_adj(0); pack_adj();
    load_x(1);
    spath(bS);
    load_adj(1);

    // ---- history, pipelined: iter t does GRU(t) and S-path(t+1) ----
    for (int t = 0; t < 49; ++t) {
        f32x16 aR0, aZ0, aNi0, aNh0, aR1, aZ1, aNi1, aNh1;
        f16x8 nb0, nb1, nb2, nb3, nS[4];
        gru_mfma(0, aR0, aZ0, aNi0, aNh0);
        stage_x();                         // xL <- x(t+1)
        act(hC0, aR0, aZ0, aNi0, aNh0, nb0, nb1);
        pack_adj();                        // bA <- adj(t+1)
        const int tp = (t + 2 < 50) ? t + 2 : 49;   // clamp: keeps body branch-free
        load_adj(tp); load_x(tp);          // c <- adj(t+2), pfx <- x(t+2)
        spath(nS);                         // bS_next = S(t+1), overlaps GRU/act
        gru_mfma(1, aR1, aZ1, aNi1, aNh1);
        act(hC1, aR1, aZ1, aNi1, aNh1, nb2, nb3);
        bH[0] = nb0; bH[1] = nb1; bH[2] = nb2; bH[3] = nb3;
        bS[0] = nS[0]; bS[1] = nS[1]; bS[2] = nS[2]; bS[3] = nS[3];
    }

    // ---- t = 49: last history GRU (bS = S(49), bA = adj(49), xL = x(49)) ----
    {
        f32x16 aR0, aZ0, aNi0, aNh0, aR1, aZ1, aNi1, aNh1;
        f16x8 nb0, nb1, nb2, nb3;
        gru_mfma(0, aR0, aZ0, aNi0, aNh0);
        act(hC0, aR0, aZ0, aNi0, aNh0, nb0, nb1);
        gru_mfma(1, aR1, aZ1, aNi1, aNh1);
        act(hC1, aR1, aZ1, aNi1, aNh1, nb2, nb3);
        bH[0] = nb0; bH[1] = nb1; bH[2] = nb2; bH[3] = nb3;
    }

    // ---- future: serial (decode(t) feeds x(t+1)); adj frags fixed at t=49 ----
    for (int fs = 0; fs < 10; ++fs) {
        spath(bS);
        f32x16 aR0, aZ0, aNi0, aNh0, aR1, aZ1, aNi1, aNh1;
        f16x8 nb0, nb1, nb2, nb3;
        gru_mfma(0, aR0, aZ0, aNi0, aNh0);
        act(hC0, aR0, aZ0, aNi0, aNh0, nb0, nb1);
        gru_mfma(1, aR1, aZ1, aNi1, aNh1);
        act(hC1, aR1, aZ1, aNi1, aNh1, nb2, nb3);
        bH[0] = nb0; bH[1] = nb1; bH[2] = nb2; bH[3] = nb3;

        f32x16 d1 = z16;
        #pragma unroll
        for (int kt = 0; kt < 4; ++kt) d1 = mm(d1, 60 + kt, bH[kt]);
        d1 = mm(d1, 64, bC);
        #pragma unroll
        for (int i = 0; i < 16; ++i) d1[i] = fmaxf(d1[i], 0.f);
        f16x8 bD0, bD1;
        cvt_tile(d1, bD0, bD1);
        f32x16 d2 = z16;
        d2 = mm(d2, 65, bD0);
        d2 = mm(d2, 66, bD1);
        d2 = mm(d2, 67, bC);
        if (hf == 0 && l31 < 23) {
            f32x4n o;
            o[0] = d2[0]; o[1] = d2[1]; o[2] = d2[2]; o[3] = d2[3];
            *(f32x4n*)(outb + fs * 92 + l31 * 4) = o;
            *(f32x4n*)(xL + l31 * 4) = o;     // feeds next step's X^
        }
    }
}

extern "C" void kernel_launch(void* const* d_in, const int* in_sizes, int n_in,
                              void* d_out, int out_size, void* d_ws, size_t ws_size,
                              hipStream_t stream) {
    (void)in_sizes; (void)n_in; (void)d_ws; (void)ws_size; (void)out_size;
    hipFuncSetAttribute((const void*)gwm_kernel,
                        hipFuncAttributeMaxDynamicSharedMemorySize, SMEM_BYTES);
    gwm_kernel<<<dim3(256), dim3(512), SMEM_BYTES, stream>>>(
        (const float*)d_in[0], (const float*)d_in[1], (const float*)d_in[2],
        (const float*)d_in[3], (const float*)d_in[4], (const float*)d_in[5],
        (const float*)d_in[6], (const float*)d_in[7], (const float*)d_in[8],
        (const float*)d_in[9], (const float*)d_in[10], (const float*)d_in[11],
        (float*)d_out);
}

// Round 4
// 732.295 us; speedup vs baseline: 1.0020x; 1.0020x over previous
//
#include <hip/hip_runtime.h>
#include <stdint.h>

// GenerativeWorldModel: B=2048,T=50,N=23,F=4,H=64,FUT=10. All I/O fp32.
// 1 wave = 1 batch, 512 thr/block (8 waves), 256 blocks, no barriers in loop.
// All GEMMs transposed (D[row=feature][col=node]); h recurrence in registers.
// R4 vs R3: __launch_bounds__(512,2)->(512,1). The backend derives
//   waves/EU = (min_blocks * threads/64) / 4, so "2" forced a 128-VGPR cap
//   and the pipelined schedule (~190 live) spilled 427 MB/dispatch to
//   scratch (R3: WRITE_SIZE 7.4->434.8 MB, dur 343->523us). Grid is 1
//   block/CU (256 blocks/256 CUs) so the cap change costs no occupancy.
// R3 vs baseline (343us/dispatch):
//  1) cvt_tile via two-arg v_permlane32_swap: swap(u0,u2) returns
//     {word0, word2} of the B-frag directly -- 4 VALU permlanes replace
//     4 ds_bpermute + cndmasks.
//  2) adj LDS staging (div-23 transpose + ds round trip) -> direct per-row
//     global loads into registers; bA frags packed straight from regs.
//  3) software pipeline: S-path(t+1) (x/adj -> E -> S) is h-independent, so
//     it runs between GRU-MFMA(t) and the trans-heavy activations of t.

typedef _Float16 f16;
typedef f16   f16x2  __attribute__((ext_vector_type(2)));
typedef f16   f16x8  __attribute__((ext_vector_type(8)));
typedef float f32x4n __attribute__((ext_vector_type(4)));
typedef float f32x16 __attribute__((ext_vector_type(16)));
typedef int   i32x2  __attribute__((ext_vector_type(2)));
typedef float f32x4u __attribute__((ext_vector_type(4), aligned(4)));

#define WBYTES 69632            // 68 weight frags * 1024 B
#define PW 512                  // per-wave: xL f32[128]
#define SMEM_BYTES (WBYTES + 8 * PW)   // 73728

static __device__ __forceinline__ unsigned pk2(float a, float b) {
    f16x2 h; h[0] = (f16)a; h[1] = (f16)b;
    return __builtin_bit_cast(unsigned, h);
}
static __device__ __forceinline__ f16x8 mkfrag(unsigned a, unsigned b, unsigned c, unsigned d) {
    uint4 u = make_uint4(a, b, c, d);
    return __builtin_bit_cast(f16x8, u);
}
// v_permlane32_swap(a,b): exchanges hi-half(a) with lo-half(b).
// r0 = {a.lo | b.lo-values in hi lanes}, r1 = {a.hi-values in lo lanes | b.hi}
static __device__ __forceinline__ void pswap2(unsigned a, unsigned b,
                                              unsigned& r0, unsigned& r1) {
    auto r = __builtin_amdgcn_permlane32_swap((int)a, (int)b, false, false);
    i32x2 v = __builtin_bit_cast(i32x2, r);
    r0 = (unsigned)v[0]; r1 = (unsigned)v[1];
}
// hi-dup of x: every lane gets x from lane 32|(l&31)  (valid for lo lanes)
static __device__ __forceinline__ unsigned dup_hi(unsigned x) {
    unsigned r0, r1; pswap2(x, x, r0, r1); return r1;
}

static __device__ __forceinline__ float sigm(float x) {
    return __builtin_amdgcn_rcpf(1.f + __expf(-x));
}
static __device__ __forceinline__ float tanhp(float x) {
    return 1.f - 2.f * __builtin_amdgcn_rcpf(1.f + __expf(2.f * x));
}
// C-layout f32x16 tile (row=(i&3)+8*(i>>2)+4*hf, col=l31) -> two B-frags
// fe = tile rows 0..15, fo = rows 16..31.  Lane mapping:
//   fe(lo lanes) = (lo.u0, lo.u1, hi.u0, hi.u1)   [rows 0-3, 4-7]
//   fe(hi lanes) = (lo.u2, lo.u3, hi.u2, hi.u3)   [rows 8-11, 12-15]
// pswap2(u0,u2) yields exactly (word0, word2); pswap2(u1,u3) -> (word1, word3).
static __device__ __forceinline__ void cvt_tile(const f32x16& v, f16x8& fe, f16x8& fo) {
    unsigned e0, e1, e2, e3, o0, o1, o2, o3;
    pswap2(pk2(v[0], v[1]),   pk2(v[4], v[5]),   e0, e2);
    pswap2(pk2(v[2], v[3]),   pk2(v[6], v[7]),   e1, e3);
    pswap2(pk2(v[8], v[9]),   pk2(v[12], v[13]), o0, o2);
    pswap2(pk2(v[10], v[11]), pk2(v[14], v[15]), o1, o3);
    fe = mkfrag(e0, e1, e2, e3);
    fo = mkfrag(o0, o1, o2, o3);
}

__global__ __launch_bounds__(512, 1) void gwm_kernel(
    const float* __restrict__ xseq, const float* __restrict__ adjseq,
    const float* __restrict__ Wg,  const float* __restrict__ bg,
    const float* __restrict__ Wih, const float* __restrict__ Whh,
    const float* __restrict__ bih, const float* __restrict__ bhh,
    const float* __restrict__ Wd1, const float* __restrict__ bd1,
    const float* __restrict__ Wd2, const float* __restrict__ bd2,
    float* __restrict__ out)
{
    extern __shared__ char smem[];
    const int tid  = threadIdx.x;
    const int lane = tid & 63;
    const int wv   = tid >> 6;
    const int l31  = lane & 31;
    const int hf   = lane >> 5;

    // ---- pack weights (A-frags, fp16) + bias columns into LDS (once) ----
    for (int idx = tid; idx < 68 * 64; idx += 512) {
        const int fi = idx >> 6, l = idx & 63, ln = l & 31, lh = l >> 5;
        float v[8];
        #pragma unroll
        for (int j = 0; j < 8; ++j) v[j] = 0.f;
        if (fi < 60) {
            const int grp = fi / 5, kt = fi - grp * 5;
            const int side = grp / 6, tau = grp - side * 6;
            const float* W = side ? Whh : Wih;
            const int row = tau * 32 + ln;
            if (kt < 4) {
                const float* s = W + row * 64 + kt * 16 + lh * 8;
                #pragma unroll
                for (int j = 0; j < 8; ++j) v[j] = s[j];
            } else if (lh == 0) {
                if (side == 0) v[0] = bih[row] + (tau < 4 ? bhh[row] : 0.f);
                else           v[0] = (tau < 4) ? 0.f : bhh[row];
            }
        } else if (fi < 65) {
            const int kt = fi - 60;
            if (kt < 4) {
                const float* s = Wd1 + ln * 64 + kt * 16 + lh * 8;
                #pragma unroll
                for (int j = 0; j < 8; ++j) v[j] = s[j];
            } else if (lh == 0) v[0] = bd1[ln];
        } else {
            const int kt = fi - 65;
            if (kt < 2) {
                if (ln < 4) {
                    const float* s = Wd2 + ln * 32 + kt * 16 + lh * 8;
                    #pragma unroll
                    for (int j = 0; j < 8; ++j) v[j] = s[j];
                }
            } else if (lh == 0 && ln < 4) v[0] = bd2[ln];
        }
        f16x8 h8;
        #pragma unroll
        for (int j = 0; j < 8; ++j) h8[j] = (f16)v[j];
        *(f16x8*)(smem + fi * 1024 + l * 16) = h8;
    }

    float* xL = (float*)(smem + WBYTES + wv * PW);   // f32[128] (92 real + zero pad)
    xL[lane] = 0.f; xL[lane + 64] = 0.f;
    __syncthreads();   // weight frags visible

    // ---- per-lane constants ----
    const f16x8 bC = (hf == 0) ? mkfrag(pk2(1.f, 0.f), 0u, 0u, 0u)
                               : mkfrag(0u, 0u, 0u, 0u);
    f16x8 aWg0, aWg1;
    {
        const int c0 = l31, c1 = 32 + l31;
        aWg0 = hf ? mkfrag(0u,0u,0u,0u)
                  : mkfrag(pk2(Wg[c0*4], Wg[c0*4+1]), pk2(Wg[c0*4+2], Wg[c0*4+3]),
                           pk2(bg[c0], 0.f), 0u);
        aWg1 = hf ? mkfrag(0u,0u,0u,0u)
                  : mkfrag(pk2(Wg[c1*4], Wg[c1*4+1]), pk2(Wg[c1*4+2], Wg[c1*4+3]),
                           pk2(bg[c1], 0.f), 0u);
    }

    const int b = blockIdx.x * 8 + wv;
    const float* xg = xseq   + (size_t)b * (50 * 92);
    const float* ag = adjseq + (size_t)b * (50 * 529);
    float* outb = out + (size_t)b * 920;

    // ---- recurrent state ----
    f32x16 hC0, hC1;
    f16x8  bH[4];
    f16x8  bS[4];
    f16x8  bA0, bA1;       // adj^T B-frags for the t currently in the S-path
    float  c[16];          // adj row prefetch: lane needs row l31 cols [8hf,8hf+8)+[16+8hf,...)
    f32x4n pfx;
    #pragma unroll
    for (int i = 0; i < 16; ++i) { hC0[i] = 0.f; hC1[i] = 0.f; }
    #pragma unroll
    for (int kt = 0; kt < 4; ++kt) bH[kt] = mkfrag(0u, 0u, 0u, 0u);

    f32x16 z16;
    #pragma unroll
    for (int i = 0; i < 16; ++i) z16[i] = 0.f;

    auto mm = [&](f32x16 acc, int fi, f16x8 bfr) -> f32x16 {
        const f16x8 aW = *(const f16x8*)(smem + fi * 1024 + lane * 16);
        return __builtin_amdgcn_mfma_f32_32x32x16_f16(aW, bfr, acc, 0, 0, 0);
    };

    // direct global->reg adj row load (replaces LDS staging + div-23 transpose)
    auto load_adj = [&](int t) {
        #pragma unroll
        for (int i = 0; i < 16; ++i) c[i] = 0.f;
        if (l31 < 23) {
            const float* ar = ag + t * 529 + l31 * 23 + 8 * hf;
            f32x4u u0 = *(const f32x4u*)ar;
            f32x4u u1 = *(const f32x4u*)(ar + 4);
            c[0]=u0[0]; c[1]=u0[1]; c[2]=u0[2]; c[3]=u0[3];
            c[4]=u1[0]; c[5]=u1[1]; c[6]=u1[2]; c[7]=u1[3];
            if (hf == 0) {                 // cols 16..22 (col 23 stays 0)
                f32x4u u2 = *(const f32x4u*)(ar + 16);
                c[8]=u2[0]; c[9]=u2[1]; c[10]=u2[2]; c[11]=u2[3];
                c[12]=ar[20]; c[13]=ar[21]; c[14]=ar[22];
            }                              // hf==1: cols 24..31 are pad -> 0
        }
    };
    auto pack_adj = [&]() {
        bA0 = mkfrag(pk2(c[0],c[1]),  pk2(c[2],c[3]),   pk2(c[4],c[5]),   pk2(c[6],c[7]));
        bA1 = mkfrag(pk2(c[8],c[9]),  pk2(c[10],c[11]), pk2(c[12],c[13]), pk2(c[14],c[15]));
    };
    auto load_x  = [&](int t) {
        if (lane < 23) pfx = *(const f32x4n*)(xg + t * 92 + 4 * lane);
    };
    auto stage_x = [&]() {
        if (lane < 23) *(f32x4n*)(xL + 4 * lane) = pfx;
    };

    // S-path: xL + bA -> bS frags (h-independent)
    auto spath = [&](f16x8* bSo) {
        f16x8 aX0, aX1;
        {
            float v0[8], v1[8];
            #pragma unroll
            for (int j = 0; j < 8; ++j) {
                const int n0 = 8 * hf + j, n1 = 16 + 8 * hf + j;
                const float x0 = xL[n0 * 4 + (l31 & 3)];
                const float x1 = xL[n1 * 4 + (l31 & 3)];
                v0[j] = (l31 < 4) ? x0 : ((l31 == 4) ? 1.f : 0.f);
                v1[j] = (l31 < 4) ? x1 : ((l31 == 4) ? 1.f : 0.f);
            }
            aX0 = mkfrag(pk2(v0[0],v0[1]), pk2(v0[2],v0[3]), pk2(v0[4],v0[5]), pk2(v0[6],v0[7]));
            aX1 = mkfrag(pk2(v1[0],v1[1]), pk2(v1[2],v1[3]), pk2(v1[4],v1[5]), pk2(v1[6],v1[7]));
        }
        f32x16 accE = z16;
        accE = __builtin_amdgcn_mfma_f32_32x32x16_f16(aX0, bA0, accE, 0, 0, 0);
        accE = __builtin_amdgcn_mfma_f32_32x32x16_f16(aX1, bA1, accE, 0, 0, 0);
        const unsigned p01 = pk2(accE[0], accE[1]), p23 = pk2(accE[2], accE[3]);
        const unsigned p4  = dup_hi(pk2(accE[0], 0.f));   // row4 lives in hi half
        const f16x8 bE = hf ? mkfrag(0u, 0u, 0u, 0u) : mkfrag(p01, p23, p4, 0u);
        f32x16 s0 = z16, s1 = z16;
        s0 = __builtin_amdgcn_mfma_f32_32x32x16_f16(aWg0, bE, s0, 0, 0, 0);
        s1 = __builtin_amdgcn_mfma_f32_32x32x16_f16(aWg1, bE, s1, 0, 0, 0);
        #pragma unroll
        for (int i = 0; i < 16; ++i) { s0[i] = fmaxf(s0[i], 0.f); s1[i] = fmaxf(s1[i], 0.f); }
        cvt_tile(s0, bSo[0], bSo[1]);
        cvt_tile(s1, bSo[2], bSo[3]);
    };

    auto gru_mfma = [&](int hnum, f32x16& aR, f32x16& aZ, f32x16& aNi, f32x16& aNh) {
        const int tR = hnum, tZ = 2 + hnum, tN = 4 + hnum;
        aR = z16; aZ = z16; aNi = z16; aNh = z16;
        #pragma unroll
        for (int kt = 0; kt < 4; ++kt) {
            aR  = mm(aR,  (0 * 6 + tR) * 5 + kt, bS[kt]);
            aR  = mm(aR,  (1 * 6 + tR) * 5 + kt, bH[kt]);
            aZ  = mm(aZ,  (0 * 6 + tZ) * 5 + kt, bS[kt]);
            aZ  = mm(aZ,  (1 * 6 + tZ) * 5 + kt, bH[kt]);
            aNi = mm(aNi, (0 * 6 + tN) * 5 + kt, bS[kt]);
            aNh = mm(aNh, (1 * 6 + tN) * 5 + kt, bH[kt]);
        }
        aR  = mm(aR,  (0 * 6 + tR) * 5 + 4, bC);
        aZ  = mm(aZ,  (0 * 6 + tZ) * 5 + 4, bC);
        aNi = mm(aNi, (0 * 6 + tN) * 5 + 4, bC);
        aNh = mm(aNh, (1 * 6 + tN) * 5 + 4, bC);
    };
    auto act = [&](f32x16& hv, const f32x16& aR, const f32x16& aZ,
                   const f32x16& aNi, const f32x16& aNh, f16x8& nbe, f16x8& nbo) {
        #pragma unroll
        for (int i = 0; i < 16; ++i) {
            const float r = sigm(aR[i]);
            const float z = sigm(aZ[i]);
            const float n = tanhp(aNi[i] + r * aNh[i]);
            hv[i] = n + z * (hv[i] - n);
        }
        cvt_tile(hv, nbe, nbo);
    };

    // ---- prologue: S(0) + prefetch t=1 ----
    load_x(0); stage_x();
    load_adj(0); pack_adj();
    load_x(1);
    spath(bS);
    load_adj(1);

    // ---- history, pipelined: iter t does GRU(t) and S-path(t+1) ----
    for (int t = 0; t < 49; ++t) {
        f32x16 aR0, aZ0, aNi0, aNh0, aR1, aZ1, aNi1, aNh1;
        f16x8 nb0, nb1, nb2, nb3, nS[4];
        gru_mfma(0, aR0, aZ0, aNi0, aNh0);
        stage_x();                         // xL <- x(t+1)
        act(hC0, aR0, aZ0, aNi0, aNh0, nb0, nb1);
        pack_adj();                        // bA <- adj(t+1)
        const int tp = (t + 2 < 50) ? t + 2 : 49;   // clamp: keeps body branch-free
        load_adj(tp); load_x(tp);          // c <- adj(t+2), pfx <- x(t+2)
        spath(nS);                         // bS_next = S(t+1), overlaps GRU/act
        gru_mfma(1, aR1, aZ1, aNi1, aNh1);
        act(hC1, aR1, aZ1, aNi1, aNh1, nb2, nb3);
        bH[0] = nb0; bH[1] = nb1; bH[2] = nb2; bH[3] = nb3;
        bS[0] = nS[0]; bS[1] = nS[1]; bS[2] = nS[2]; bS[3] = nS[3];
    }

    // ---- t = 49: last history GRU (bS = S(49), bA = adj(49), xL = x(49)) ----
    {
        f32x16 aR0, aZ0, aNi0, aNh0, aR1, aZ1, aNi1, aNh1;
        f16x8 nb0, nb1, nb2, nb3;
        gru_mfma(0, aR0, aZ0, aNi0, aNh0);
        act(hC0, aR0, aZ0, aNi0, aNh0, nb0, nb1);
        gru_mfma(1, aR1, aZ1, aNi1, aNh1);
        act(hC1, aR1, aZ1, aNi1, aNh1, nb2, nb3);
        bH[0] = nb0; bH[1] = nb1; bH[2] = nb2; bH[3] = nb3;
    }

    // ---- future: serial (decode(t) feeds x(t+1)); adj frags fixed at t=49 ----
    for (int fs = 0; fs < 10; ++fs) {
        spath(bS);
        f32x16 aR0, aZ0, aNi0, aNh0, aR1, aZ1, aNi1, aNh1;
        f16x8 nb0, nb1, nb2, nb3;
        gru_mfma(0, aR0, aZ0, aNi0, aNh0);
        act(hC0, aR0, aZ0, aNi0, aNh0, nb0, nb1);
        gru_mfma(1, aR1, aZ1, aNi1, aNh1);
        act(hC1, aR1, aZ1, aNi1, aNh1, nb2, nb3);
        bH[0] = nb0; bH[1] = nb1; bH[2] = nb2; bH[3] = nb3;

        f32x16 d1 = z16;
        #pragma unroll
        for (int kt = 0; kt < 4; ++kt) d1 = mm(d1, 60 + kt, bH[kt]);
        d1 = mm(d1, 64, bC);
        #pragma unroll
        for (int i = 0; i < 16; ++i) d1[i] = fmaxf(d1[i], 0.f);
        f16x8 bD0, bD1;
        cvt_tile(d1, bD0, bD1);
        f32x16 d2 = z16;
        d2 = mm(d2, 65, bD0);
        d2 = mm(d2, 66, bD1);
        d2 = mm(d2, 67, bC);
        if (hf == 0 && l31 < 23) {
            f32x4n o;
            o[0] = d2[0]; o[1] = d2[1]; o[2] = d2[2]; o[3] = d2[3];
            *(f32x4n*)(outb + fs * 92 + l31 * 4) = o;
            *(f32x4n*)(xL + l31 * 4) = o;     // feeds next step's X^
        }
    }
}

extern "C" void kernel_launch(void* const* d_in, const int* in_sizes, int n_in,
                              void* d_out, int out_size, void* d_ws, size_t ws_size,
                              hipStream_t stream) {
    (void)in_sizes; (void)n_in; (void)d_ws; (void)ws_size; (void)out_size;
    hipFuncSetAttribute((const void*)gwm_kernel,
                        hipFuncAttributeMaxDynamicSharedMemorySize, SMEM_BYTES);
    gwm_kernel<<<dim3(256), dim3(512), SMEM_BYTES, stream>>>(
        (const float*)d_in[0], (const float*)d_in[1], (const float*)d_in[2],
        (const float*)d_in[3], (const float*)d_in[4], (const float*)d_in[5],
        (const float*)d_in[6], (const float*)d_in[7], (const float*)d_in[8],
        (const float*)d_in[9], (const float*)d_in[10], (const float*)d_in[11],
        (float*)d_out);
}

// Round 5
// 731.687 us; speedup vs baseline: 1.0028x; 1.0008x over previous
//
#include <hip/hip_runtime.h>
#include <stdint.h>

// GenerativeWorldModel: B=2048,T=50,N=23,F=4,H=64,FUT=10. All I/O fp32.
// 1 wave = 1 batch, 512 thr/block (8 waves), 256 blocks, no barriers in loop.
// All GEMMs transposed (D[row=feature][col=node]); h recurrence in registers.
// R5 vs R3/R4: scratch traffic (WRITE_SIZE 7.4->433 MB) was SROA failure,
//   not a VGPR cap: spath took f16x8* (nS/bS decayed to pointers) ->
//   address-taken arrays demoted to scratch (~64B/lane/iter = the 426MB).
//   Launch-bounds changes did nothing (R4 == R3 codegen), confirming cap
//   wasn't binding. Fix: spath writes 4 named f16x8& refs; bS/bH arrays ->
//   named scalars; gru kt-loop macro-unrolled. Budget pinned via
//   amdgpu_waves_per_eu(2,2) (= actual occupancy, 1 block/CU).
// R3 vs baseline (343us/dispatch):
//  1) cvt_tile via two-arg v_permlane32_swap (4 VALU ops replace 4
//     ds_bpermute + cndmasks).
//  2) adj LDS staging (div-23 transpose + ds round trip) -> direct per-row
//     global loads into registers; bA frags packed straight from regs.
//  3) software pipeline: S-path(t+1) (x/adj -> E -> S) is h-independent, so
//     it runs between GRU-MFMA(t) and the trans-heavy activations of t.

typedef _Float16 f16;
typedef f16   f16x2  __attribute__((ext_vector_type(2)));
typedef f16   f16x8  __attribute__((ext_vector_type(8)));
typedef float f32x4n __attribute__((ext_vector_type(4)));
typedef float f32x16 __attribute__((ext_vector_type(16)));
typedef int   i32x2  __attribute__((ext_vector_type(2)));
typedef float f32x4u __attribute__((ext_vector_type(4), aligned(4)));

#define WBYTES 69632            // 68 weight frags * 1024 B
#define PW 512                  // per-wave: xL f32[128]
#define SMEM_BYTES (WBYTES + 8 * PW)   // 73728

static __device__ __forceinline__ unsigned pk2(float a, float b) {
    f16x2 h; h[0] = (f16)a; h[1] = (f16)b;
    return __builtin_bit_cast(unsigned, h);
}
static __device__ __forceinline__ f16x8 mkfrag(unsigned a, unsigned b, unsigned c, unsigned d) {
    uint4 u = make_uint4(a, b, c, d);
    return __builtin_bit_cast(f16x8, u);
}
// v_permlane32_swap(a,b): exchanges hi-half(a) with lo-half(b).
// r0 = {a.lo | b.lo-values in hi lanes}, r1 = {a.hi-values in lo lanes | b.hi}
static __device__ __forceinline__ void pswap2(unsigned a, unsigned b,
                                              unsigned& r0, unsigned& r1) {
    auto r = __builtin_amdgcn_permlane32_swap((int)a, (int)b, false, false);
    i32x2 v = __builtin_bit_cast(i32x2, r);
    r0 = (unsigned)v[0]; r1 = (unsigned)v[1];
}
// hi-dup of x: every lane gets x from lane 32|(l&31)  (valid for lo lanes)
static __device__ __forceinline__ unsigned dup_hi(unsigned x) {
    unsigned r0, r1; pswap2(x, x, r0, r1); return r1;
}

static __device__ __forceinline__ float sigm(float x) {
    return __builtin_amdgcn_rcpf(1.f + __expf(-x));
}
static __device__ __forceinline__ float tanhp(float x) {
    return 1.f - 2.f * __builtin_amdgcn_rcpf(1.f + __expf(2.f * x));
}
// C-layout f32x16 tile (row=(i&3)+8*(i>>2)+4*hf, col=l31) -> two B-frags
// fe = tile rows 0..15, fo = rows 16..31.  Lane mapping:
//   fe(lo lanes) = (lo.u0, lo.u1, hi.u0, hi.u1)   [rows 0-3, 4-7]
//   fe(hi lanes) = (lo.u2, lo.u3, hi.u2, hi.u3)   [rows 8-11, 12-15]
// pswap2(u0,u2) yields exactly (word0, word2); pswap2(u1,u3) -> (word1, word3).
static __device__ __forceinline__ void cvt_tile(const f32x16& v, f16x8& fe, f16x8& fo) {
    unsigned e0, e1, e2, e3, o0, o1, o2, o3;
    pswap2(pk2(v[0], v[1]),   pk2(v[4], v[5]),   e0, e2);
    pswap2(pk2(v[2], v[3]),   pk2(v[6], v[7]),   e1, e3);
    pswap2(pk2(v[8], v[9]),   pk2(v[12], v[13]), o0, o2);
    pswap2(pk2(v[10], v[11]), pk2(v[14], v[15]), o1, o3);
    fe = mkfrag(e0, e1, e2, e3);
    fo = mkfrag(o0, o1, o2, o3);
}

__global__ __launch_bounds__(512)
__attribute__((amdgpu_waves_per_eu(2, 2)))
void gwm_kernel(
    const float* __restrict__ xseq, const float* __restrict__ adjseq,
    const float* __restrict__ Wg,  const float* __restrict__ bg,
    const float* __restrict__ Wih, const float* __restrict__ Whh,
    const float* __restrict__ bih, const float* __restrict__ bhh,
    const float* __restrict__ Wd1, const float* __restrict__ bd1,
    const float* __restrict__ Wd2, const float* __restrict__ bd2,
    float* __restrict__ out)
{
    extern __shared__ char smem[];
    const int tid  = threadIdx.x;
    const int lane = tid & 63;
    const int wv   = tid >> 6;
    const int l31  = lane & 31;
    const int hf   = lane >> 5;

    // ---- pack weights (A-frags, fp16) + bias columns into LDS (once) ----
    for (int idx = tid; idx < 68 * 64; idx += 512) {
        const int fi = idx >> 6, l = idx & 63, ln = l & 31, lh = l >> 5;
        float v[8];
        #pragma unroll
        for (int j = 0; j < 8; ++j) v[j] = 0.f;
        if (fi < 60) {
            const int grp = fi / 5, kt = fi - grp * 5;
            const int side = grp / 6, tau = grp - side * 6;
            const float* W = side ? Whh : Wih;
            const int row = tau * 32 + ln;
            if (kt < 4) {
                const float* s = W + row * 64 + kt * 16 + lh * 8;
                #pragma unroll
                for (int j = 0; j < 8; ++j) v[j] = s[j];
            } else if (lh == 0) {
                if (side == 0) v[0] = bih[row] + (tau < 4 ? bhh[row] : 0.f);
                else           v[0] = (tau < 4) ? 0.f : bhh[row];
            }
        } else if (fi < 65) {
            const int kt = fi - 60;
            if (kt < 4) {
                const float* s = Wd1 + ln * 64 + kt * 16 + lh * 8;
                #pragma unroll
                for (int j = 0; j < 8; ++j) v[j] = s[j];
            } else if (lh == 0) v[0] = bd1[ln];
        } else {
            const int kt = fi - 65;
            if (kt < 2) {
                if (ln < 4) {
                    const float* s = Wd2 + ln * 32 + kt * 16 + lh * 8;
                    #pragma unroll
                    for (int j = 0; j < 8; ++j) v[j] = s[j];
                }
            } else if (lh == 0 && ln < 4) v[0] = bd2[ln];
        }
        f16x8 h8;
        #pragma unroll
        for (int j = 0; j < 8; ++j) h8[j] = (f16)v[j];
        *(f16x8*)(smem + fi * 1024 + l * 16) = h8;
    }

    float* xL = (float*)(smem + WBYTES + wv * PW);   // f32[128] (92 real + zero pad)
    xL[lane] = 0.f; xL[lane + 64] = 0.f;
    __syncthreads();   // weight frags visible

    // ---- per-lane constants ----
    const f16x8 bC = (hf == 0) ? mkfrag(pk2(1.f, 0.f), 0u, 0u, 0u)
                               : mkfrag(0u, 0u, 0u, 0u);
    f16x8 aWg0, aWg1;
    {
        const int c0 = l31, c1 = 32 + l31;
        aWg0 = hf ? mkfrag(0u,0u,0u,0u)
                  : mkfrag(pk2(Wg[c0*4], Wg[c0*4+1]), pk2(Wg[c0*4+2], Wg[c0*4+3]),
                           pk2(bg[c0], 0.f), 0u);
        aWg1 = hf ? mkfrag(0u,0u,0u,0u)
                  : mkfrag(pk2(Wg[c1*4], Wg[c1*4+1]), pk2(Wg[c1*4+2], Wg[c1*4+3]),
                           pk2(bg[c1], 0.f), 0u);
    }

    const int b = blockIdx.x * 8 + wv;
    const float* xg = xseq   + (size_t)b * (50 * 92);
    const float* ag = adjseq + (size_t)b * (50 * 529);
    float* outb = out + (size_t)b * 920;

    // ---- recurrent state (all named scalars: no address-taken arrays) ----
    f32x16 hC0, hC1;
    f16x8  bH0, bH1, bH2, bH3;
    f16x8  bS0, bS1, bS2, bS3;
    f16x8  bA0, bA1;       // adj^T B-frags for the t currently in the S-path
    float  c[16];          // adj row prefetch (const-indexed only, SROA-safe)
    f32x4n pfx;
    #pragma unroll
    for (int i = 0; i < 16; ++i) { hC0[i] = 0.f; hC1[i] = 0.f; }
    bH0 = bH1 = bH2 = bH3 = mkfrag(0u, 0u, 0u, 0u);

    f32x16 z16;
    #pragma unroll
    for (int i = 0; i < 16; ++i) z16[i] = 0.f;

    auto mm = [&](f32x16 acc, int fi, f16x8 bfr) -> f32x16 {
        const f16x8 aW = *(const f16x8*)(smem + fi * 1024 + lane * 16);
        return __builtin_amdgcn_mfma_f32_32x32x16_f16(aW, bfr, acc, 0, 0, 0);
    };

    // direct global->reg adj row load (replaces LDS staging + div-23 transpose)
    auto load_adj = [&](int t) {
        #pragma unroll
        for (int i = 0; i < 16; ++i) c[i] = 0.f;
        if (l31 < 23) {
            const float* ar = ag + t * 529 + l31 * 23 + 8 * hf;
            f32x4u u0 = *(const f32x4u*)ar;
            f32x4u u1 = *(const f32x4u*)(ar + 4);
            c[0]=u0[0]; c[1]=u0[1]; c[2]=u0[2]; c[3]=u0[3];
            c[4]=u1[0]; c[5]=u1[1]; c[6]=u1[2]; c[7]=u1[3];
            if (hf == 0) {                 // cols 16..22 (col 23 stays 0)
                f32x4u u2 = *(const f32x4u*)(ar + 16);
                c[8]=u2[0]; c[9]=u2[1]; c[10]=u2[2]; c[11]=u2[3];
                c[12]=ar[20]; c[13]=ar[21]; c[14]=ar[22];
            }                              // hf==1: cols 24..31 are pad -> 0
        }
    };
    auto pack_adj = [&]() {
        bA0 = mkfrag(pk2(c[0],c[1]),  pk2(c[2],c[3]),   pk2(c[4],c[5]),   pk2(c[6],c[7]));
        bA1 = mkfrag(pk2(c[8],c[9]),  pk2(c[10],c[11]), pk2(c[12],c[13]), pk2(c[14],c[15]));
    };
    auto load_x  = [&](int t) {
        if (lane < 23) pfx = *(const f32x4n*)(xg + t * 92 + 4 * lane);
    };
    auto stage_x = [&]() {
        if (lane < 23) *(f32x4n*)(xL + 4 * lane) = pfx;
    };

    // S-path: xL + bA -> 4 named B-frags (h-independent). No pointer params.
    auto spath = [&](f16x8& o0, f16x8& o1, f16x8& o2, f16x8& o3) {
        f16x8 aX0, aX1;
        {
            float v0[8], v1[8];
            #pragma unroll
            for (int j = 0; j < 8; ++j) {
                const int n0 = 8 * hf + j, n1 = 16 + 8 * hf + j;
                const float x0 = xL[n0 * 4 + (l31 & 3)];
                const float x1 = xL[n1 * 4 + (l31 & 3)];
                v0[j] = (l31 < 4) ? x0 : ((l31 == 4) ? 1.f : 0.f);
                v1[j] = (l31 < 4) ? x1 : ((l31 == 4) ? 1.f : 0.f);
            }
            aX0 = mkfrag(pk2(v0[0],v0[1]), pk2(v0[2],v0[3]), pk2(v0[4],v0[5]), pk2(v0[6],v0[7]));
            aX1 = mkfrag(pk2(v1[0],v1[1]), pk2(v1[2],v1[3]), pk2(v1[4],v1[5]), pk2(v1[6],v1[7]));
        }
        f32x16 accE = z16;
        accE = __builtin_amdgcn_mfma_f32_32x32x16_f16(aX0, bA0, accE, 0, 0, 0);
        accE = __builtin_amdgcn_mfma_f32_32x32x16_f16(aX1, bA1, accE, 0, 0, 0);
        const unsigned p01 = pk2(accE[0], accE[1]), p23 = pk2(accE[2], accE[3]);
        const unsigned p4  = dup_hi(pk2(accE[0], 0.f));   // row4 lives in hi half
        const f16x8 bE = hf ? mkfrag(0u, 0u, 0u, 0u) : mkfrag(p01, p23, p4, 0u);
        f32x16 s0 = z16, s1 = z16;
        s0 = __builtin_amdgcn_mfma_f32_32x32x16_f16(aWg0, bE, s0, 0, 0, 0);
        s1 = __builtin_amdgcn_mfma_f32_32x32x16_f16(aWg1, bE, s1, 0, 0, 0);
        #pragma unroll
        for (int i = 0; i < 16; ++i) { s0[i] = fmaxf(s0[i], 0.f); s1[i] = fmaxf(s1[i], 0.f); }
        cvt_tile(s0, o0, o1);
        cvt_tile(s1, o2, o3);
    };

    auto gru_mfma = [&](int hnum, f32x16& aR, f32x16& aZ, f32x16& aNi, f32x16& aNh) {
        const int tR = hnum, tZ = 2 + hnum, tN = 4 + hnum;
        aR = z16; aZ = z16; aNi = z16; aNh = z16;
        #define GSTEP(kt, BS, BH) \
            aR  = mm(aR,  (0 * 6 + tR) * 5 + kt, BS); \
            aR  = mm(aR,  (1 * 6 + tR) * 5 + kt, BH); \
            aZ  = mm(aZ,  (0 * 6 + tZ) * 5 + kt, BS); \
            aZ  = mm(aZ,  (1 * 6 + tZ) * 5 + kt, BH); \
            aNi = mm(aNi, (0 * 6 + tN) * 5 + kt, BS); \
            aNh = mm(aNh, (1 * 6 + tN) * 5 + kt, BH);
        GSTEP(0, bS0, bH0)
        GSTEP(1, bS1, bH1)
        GSTEP(2, bS2, bH2)
        GSTEP(3, bS3, bH3)
        #undef GSTEP
        aR  = mm(aR,  (0 * 6 + tR) * 5 + 4, bC);
        aZ  = mm(aZ,  (0 * 6 + tZ) * 5 + 4, bC);
        aNi = mm(aNi, (0 * 6 + tN) * 5 + 4, bC);
        aNh = mm(aNh, (1 * 6 + tN) * 5 + 4, bC);
    };
    auto act = [&](f32x16& hv, const f32x16& aR, const f32x16& aZ,
                   const f32x16& aNi, const f32x16& aNh, f16x8& nbe, f16x8& nbo) {
        #pragma unroll
        for (int i = 0; i < 16; ++i) {
            const float r = sigm(aR[i]);
            const float z = sigm(aZ[i]);
            const float n = tanhp(aNi[i] + r * aNh[i]);
            hv[i] = n + z * (hv[i] - n);
        }
        cvt_tile(hv, nbe, nbo);
    };

    // ---- prologue: S(0) + prefetch t=1 ----
    load_x(0); stage_x();
    load_adj(0); pack_adj();
    load_x(1);
    spath(bS0, bS1, bS2, bS3);
    load_adj(1);

    // ---- history, pipelined: iter t does GRU(t) and S-path(t+1) ----
    for (int t = 0; t < 49; ++t) {
        f32x16 aR0, aZ0, aNi0, aNh0, aR1, aZ1, aNi1, aNh1;
        f16x8 nb0, nb1, nb2, nb3, nS0, nS1, nS2, nS3;
        gru_mfma(0, aR0, aZ0, aNi0, aNh0);
        stage_x();                         // xL <- x(t+1)
        act(hC0, aR0, aZ0, aNi0, aNh0, nb0, nb1);
        pack_adj();                        // bA <- adj(t+1)
        const int tp = (t + 2 < 50) ? t + 2 : 49;   // clamp: keeps body branch-free
        load_adj(tp); load_x(tp);          // c <- adj(t+2), pfx <- x(t+2)
        spath(nS0, nS1, nS2, nS3);         // bS_next = S(t+1), overlaps GRU/act
        gru_mfma(1, aR1, aZ1, aNi1, aNh1);
        act(hC1, aR1, aZ1, aNi1, aNh1, nb2, nb3);
        bH0 = nb0; bH1 = nb1; bH2 = nb2; bH3 = nb3;
        bS0 = nS0; bS1 = nS1; bS2 = nS2; bS3 = nS3;
    }

    // ---- t = 49: last history GRU (bS = S(49), bA = adj(49), xL = x(49)) ----
    {
        f32x16 aR0, aZ0, aNi0, aNh0, aR1, aZ1, aNi1, aNh1;
        f16x8 nb0, nb1, nb2, nb3;
        gru_mfma(0, aR0, aZ0, aNi0, aNh0);
        act(hC0, aR0, aZ0, aNi0, aNh0, nb0, nb1);
        gru_mfma(1, aR1, aZ1, aNi1, aNh1);
        act(hC1, aR1, aZ1, aNi1, aNh1, nb2, nb3);
        bH0 = nb0; bH1 = nb1; bH2 = nb2; bH3 = nb3;
    }

    // ---- future: serial (decode(t) feeds x(t+1)); adj frags fixed at t=49 ----
    for (int fs = 0; fs < 10; ++fs) {
        spath(bS0, bS1, bS2, bS3);
        f32x16 aR0, aZ0, aNi0, aNh0, aR1, aZ1, aNi1, aNh1;
        f16x8 nb0, nb1, nb2, nb3;
        gru_mfma(0, aR0, aZ0, aNi0, aNh0);
        act(hC0, aR0, aZ0, aNi0, aNh0, nb0, nb1);
        gru_mfma(1, aR1, aZ1, aNi1, aNh1);
        act(hC1, aR1, aZ1, aNi1, aNh1, nb2, nb3);
        bH0 = nb0; bH1 = nb1; bH2 = nb2; bH3 = nb3;

        f32x16 d1 = z16;
        d1 = mm(d1, 60, bH0);
        d1 = mm(d1, 61, bH1);
        d1 = mm(d1, 62, bH2);
        d1 = mm(d1, 63, bH3);
        d1 = mm(d1, 64, bC);
        #pragma unroll
        for (int i = 0; i < 16; ++i) d1[i] = fmaxf(d1[i], 0.f);
        f16x8 bD0, bD1;
        cvt_tile(d1, bD0, bD1);
        f32x16 d2 = z16;
        d2 = mm(d2, 65, bD0);
        d2 = mm(d2, 66, bD1);
        d2 = mm(d2, 67, bC);
        if (hf == 0 && l31 < 23) {
            f32x4n o;
            o[0] = d2[0]; o[1] = d2[1]; o[2] = d2[2]; o[3] = d2[3];
            *(f32x4n*)(outb + fs * 92 + l31 * 4) = o;
            *(f32x4n*)(xL + l31 * 4) = o;     // feeds next step's X^
        }
    }
}

extern "C" void kernel_launch(void* const* d_in, const int* in_sizes, int n_in,
                              void* d_out, int out_size, void* d_ws, size_t ws_size,
                              hipStream_t stream) {
    (void)in_sizes; (void)n_in; (void)d_ws; (void)ws_size; (void)out_size;
    hipFuncSetAttribute((const void*)gwm_kernel,
                        hipFuncAttributeMaxDynamicSharedMemorySize, SMEM_BYTES);
    gwm_kernel<<<dim3(256), dim3(512), SMEM_BYTES, stream>>>(
        (const float*)d_in[0], (const float*)d_in[1], (const float*)d_in[2],
        (const float*)d_in[3], (const float*)d_in[4], (const float*)d_in[5],
        (const float*)d_in[6], (const float*)d_in[7], (const float*)d_in[8],
        (const float*)d_in[9], (const float*)d_in[10], (const float*)d_in[11],
        (float*)d_out);
}

// Round 6
// 731.418 us; speedup vs baseline: 1.0032x; 1.0004x over previous
//
#include <hip/hip_runtime.h>
#include <stdint.h>

// GenerativeWorldModel: B=2048,T=50,N=23,F=4,H=64,FUT=10. All I/O fp32.
// 1 wave = 1 batch, 512 thr/block (8 waves), 256 blocks, no barriers in loop.
// All GEMMs transposed (D[row=feature][col=node]); h recurrence in registers.
// R6 vs R5: ROOT CAUSE of the 128-VGPR cap + 425MB scratch: VGPR budget is
//   LDS-OCCUPANCY-derived. R1 shrank LDS 107520->73728 B, letting 2
//   blocks/CU fit (163840/73728=2) -> compiler targets 4 waves/SIMD ->
//   VGPR cap 512/4=128 -> pipelined schedule spills. Grid is 1 block/CU
//   (256/256) so that headroom was pure loss. Fix: pad SMEM to 98304 B
//   (>81920) so 1 block/CU -> 2 waves/SIMD -> 256-VGPR budget (the R0
//   baseline's accidental config). launch_bounds(512,2) as in R0.
// R3 vs baseline (343us/dispatch):
//  1) cvt_tile via two-arg v_permlane32_swap (4 VALU ops replace 4
//     ds_bpermute + cndmasks).
//  2) adj LDS staging (div-23 transpose + ds round trip) -> direct per-row
//     global loads into registers; bA frags packed straight from regs.
//  3) software pipeline: S-path(t+1) (x/adj -> E -> S) is h-independent, so
//     it runs between GRU-MFMA(t) and the trans-heavy activations of t.

typedef _Float16 f16;
typedef f16   f16x2  __attribute__((ext_vector_type(2)));
typedef f16   f16x8  __attribute__((ext_vector_type(8)));
typedef float f32x4n __attribute__((ext_vector_type(4)));
typedef float f32x16 __attribute__((ext_vector_type(16)));
typedef int   i32x2  __attribute__((ext_vector_type(2)));
typedef float f32x4u __attribute__((ext_vector_type(4), aligned(4)));

#define WBYTES 69632            // 68 weight frags * 1024 B
#define PW 512                  // per-wave: xL f32[128]
#define SMEM_BYTES 98304        // padded past 81920 -> 1 block/CU -> 256-VGPR budget

static __device__ __forceinline__ unsigned pk2(float a, float b) {
    f16x2 h; h[0] = (f16)a; h[1] = (f16)b;
    return __builtin_bit_cast(unsigned, h);
}
static __device__ __forceinline__ f16x8 mkfrag(unsigned a, unsigned b, unsigned c, unsigned d) {
    uint4 u = make_uint4(a, b, c, d);
    return __builtin_bit_cast(f16x8, u);
}
// v_permlane32_swap(a,b): exchanges hi-half(a) with lo-half(b).
// r0 = {a.lo | b.lo-values in hi lanes}, r1 = {a.hi-values in lo lanes | b.hi}
static __device__ __forceinline__ void pswap2(unsigned a, unsigned b,
                                              unsigned& r0, unsigned& r1) {
    auto r = __builtin_amdgcn_permlane32_swap((int)a, (int)b, false, false);
    i32x2 v = __builtin_bit_cast(i32x2, r);
    r0 = (unsigned)v[0]; r1 = (unsigned)v[1];
}
// hi-dup of x: every lane gets x from lane 32|(l&31)  (valid for lo lanes)
static __device__ __forceinline__ unsigned dup_hi(unsigned x) {
    unsigned r0, r1; pswap2(x, x, r0, r1); return r1;
}

static __device__ __forceinline__ float sigm(float x) {
    return __builtin_amdgcn_rcpf(1.f + __expf(-x));
}
static __device__ __forceinline__ float tanhp(float x) {
    return 1.f - 2.f * __builtin_amdgcn_rcpf(1.f + __expf(2.f * x));
}
// C-layout f32x16 tile (row=(i&3)+8*(i>>2)+4*hf, col=l31) -> two B-frags
// fe = tile rows 0..15, fo = rows 16..31.  Lane mapping:
//   fe(lo lanes) = (lo.u0, lo.u1, hi.u0, hi.u1)   [rows 0-3, 4-7]
//   fe(hi lanes) = (lo.u2, lo.u3, hi.u2, hi.u3)   [rows 8-11, 12-15]
// pswap2(u0,u2) yields exactly (word0, word2); pswap2(u1,u3) -> (word1, word3).
static __device__ __forceinline__ void cvt_tile(const f32x16& v, f16x8& fe, f16x8& fo) {
    unsigned e0, e1, e2, e3, o0, o1, o2, o3;
    pswap2(pk2(v[0], v[1]),   pk2(v[4], v[5]),   e0, e2);
    pswap2(pk2(v[2], v[3]),   pk2(v[6], v[7]),   e1, e3);
    pswap2(pk2(v[8], v[9]),   pk2(v[12], v[13]), o0, o2);
    pswap2(pk2(v[10], v[11]), pk2(v[14], v[15]), o1, o3);
    fe = mkfrag(e0, e1, e2, e3);
    fo = mkfrag(o0, o1, o2, o3);
}

__global__ __launch_bounds__(512, 2) void gwm_kernel(
    const float* __restrict__ xseq, const float* __restrict__ adjseq,
    const float* __restrict__ Wg,  const float* __restrict__ bg,
    const float* __restrict__ Wih, const float* __restrict__ Whh,
    const float* __restrict__ bih, const float* __restrict__ bhh,
    const float* __restrict__ Wd1, const float* __restrict__ bd1,
    const float* __restrict__ Wd2, const float* __restrict__ bd2,
    float* __restrict__ out)
{
    extern __shared__ char smem[];
    const int tid  = threadIdx.x;
    const int lane = tid & 63;
    const int wv   = tid >> 6;
    const int l31  = lane & 31;
    const int hf   = lane >> 5;

    // ---- pack weights (A-frags, fp16) + bias columns into LDS (once) ----
    for (int idx = tid; idx < 68 * 64; idx += 512) {
        const int fi = idx >> 6, l = idx & 63, ln = l & 31, lh = l >> 5;
        float v[8];
        #pragma unroll
        for (int j = 0; j < 8; ++j) v[j] = 0.f;
        if (fi < 60) {
            const int grp = fi / 5, kt = fi - grp * 5;
            const int side = grp / 6, tau = grp - side * 6;
            const float* W = side ? Whh : Wih;
            const int row = tau * 32 + ln;
            if (kt < 4) {
                const float* s = W + row * 64 + kt * 16 + lh * 8;
                #pragma unroll
                for (int j = 0; j < 8; ++j) v[j] = s[j];
            } else if (lh == 0) {
                if (side == 0) v[0] = bih[row] + (tau < 4 ? bhh[row] : 0.f);
                else           v[0] = (tau < 4) ? 0.f : bhh[row];
            }
        } else if (fi < 65) {
            const int kt = fi - 60;
            if (kt < 4) {
                const float* s = Wd1 + ln * 64 + kt * 16 + lh * 8;
                #pragma unroll
                for (int j = 0; j < 8; ++j) v[j] = s[j];
            } else if (lh == 0) v[0] = bd1[ln];
        } else {
            const int kt = fi - 65;
            if (kt < 2) {
                if (ln < 4) {
                    const float* s = Wd2 + ln * 32 + kt * 16 + lh * 8;
                    #pragma unroll
                    for (int j = 0; j < 8; ++j) v[j] = s[j];
                }
            } else if (lh == 0 && ln < 4) v[0] = bd2[ln];
        }
        f16x8 h8;
        #pragma unroll
        for (int j = 0; j < 8; ++j) h8[j] = (f16)v[j];
        *(f16x8*)(smem + fi * 1024 + l * 16) = h8;
    }

    float* xL = (float*)(smem + WBYTES + wv * PW);   // f32[128] (92 real + zero pad)
    xL[lane] = 0.f; xL[lane + 64] = 0.f;
    __syncthreads();   // weight frags visible

    // ---- per-lane constants ----
    const f16x8 bC = (hf == 0) ? mkfrag(pk2(1.f, 0.f), 0u, 0u, 0u)
                               : mkfrag(0u, 0u, 0u, 0u);
    f16x8 aWg0, aWg1;
    {
        const int c0 = l31, c1 = 32 + l31;
        aWg0 = hf ? mkfrag(0u,0u,0u,0u)
                  : mkfrag(pk2(Wg[c0*4], Wg[c0*4+1]), pk2(Wg[c0*4+2], Wg[c0*4+3]),
                           pk2(bg[c0], 0.f), 0u);
        aWg1 = hf ? mkfrag(0u,0u,0u,0u)
                  : mkfrag(pk2(Wg[c1*4], Wg[c1*4+1]), pk2(Wg[c1*4+2], Wg[c1*4+3]),
                           pk2(bg[c1], 0.f), 0u);
    }

    const int b = blockIdx.x * 8 + wv;
    const float* xg = xseq   + (size_t)b * (50 * 92);
    const float* ag = adjseq + (size_t)b * (50 * 529);
    float* outb = out + (size_t)b * 920;

    // ---- recurrent state (all named scalars: no address-taken arrays) ----
    f32x16 hC0, hC1;
    f16x8  bH0, bH1, bH2, bH3;
    f16x8  bS0, bS1, bS2, bS3;
    f16x8  bA0, bA1;       // adj^T B-frags for the t currently in the S-path
    float  c[16];          // adj row prefetch (const-indexed only, SROA-safe)
    f32x4n pfx;
    #pragma unroll
    for (int i = 0; i < 16; ++i) { hC0[i] = 0.f; hC1[i] = 0.f; }
    bH0 = bH1 = bH2 = bH3 = mkfrag(0u, 0u, 0u, 0u);

    f32x16 z16;
    #pragma unroll
    for (int i = 0; i < 16; ++i) z16[i] = 0.f;

    auto mm = [&](f32x16 acc, int fi, f16x8 bfr) -> f32x16 {
        const f16x8 aW = *(const f16x8*)(smem + fi * 1024 + lane * 16);
        return __builtin_amdgcn_mfma_f32_32x32x16_f16(aW, bfr, acc, 0, 0, 0);
    };

    // direct global->reg adj row load (replaces LDS staging + div-23 transpose)
    auto load_adj = [&](int t) {
        #pragma unroll
        for (int i = 0; i < 16; ++i) c[i] = 0.f;
        if (l31 < 23) {
            const float* ar = ag + t * 529 + l31 * 23 + 8 * hf;
            f32x4u u0 = *(const f32x4u*)ar;
            f32x4u u1 = *(const f32x4u*)(ar + 4);
            c[0]=u0[0]; c[1]=u0[1]; c[2]=u0[2]; c[3]=u0[3];
            c[4]=u1[0]; c[5]=u1[1]; c[6]=u1[2]; c[7]=u1[3];
            if (hf == 0) {                 // cols 16..22 (col 23 stays 0)
                f32x4u u2 = *(const f32x4u*)(ar + 16);
                c[8]=u2[0]; c[9]=u2[1]; c[10]=u2[2]; c[11]=u2[3];
                c[12]=ar[20]; c[13]=ar[21]; c[14]=ar[22];
            }                              // hf==1: cols 24..31 are pad -> 0
        }
    };
    auto pack_adj = [&]() {
        bA0 = mkfrag(pk2(c[0],c[1]),  pk2(c[2],c[3]),   pk2(c[4],c[5]),   pk2(c[6],c[7]));
        bA1 = mkfrag(pk2(c[8],c[9]),  pk2(c[10],c[11]), pk2(c[12],c[13]), pk2(c[14],c[15]));
    };
    auto load_x  = [&](int t) {
        if (lane < 23) pfx = *(const f32x4n*)(xg + t * 92 + 4 * lane);
    };
    auto stage_x = [&]() {
        if (lane < 23) *(f32x4n*)(xL + 4 * lane) = pfx;
    };

    // S-path: xL + bA -> 4 named B-frags (h-independent). No pointer params.
    auto spath = [&](f16x8& o0, f16x8& o1, f16x8& o2, f16x8& o3) {
        f16x8 aX0, aX1;
        {
            float v0[8], v1[8];
            #pragma unroll
            for (int j = 0; j < 8; ++j) {
                const int n0 = 8 * hf + j, n1 = 16 + 8 * hf + j;
                const float x0 = xL[n0 * 4 + (l31 & 3)];
                const float x1 = xL[n1 * 4 + (l31 & 3)];
                v0[j] = (l31 < 4) ? x0 : ((l31 == 4) ? 1.f : 0.f);
                v1[j] = (l31 < 4) ? x1 : ((l31 == 4) ? 1.f : 0.f);
            }
            aX0 = mkfrag(pk2(v0[0],v0[1]), pk2(v0[2],v0[3]), pk2(v0[4],v0[5]), pk2(v0[6],v0[7]));
            aX1 = mkfrag(pk2(v1[0],v1[1]), pk2(v1[2],v1[3]), pk2(v1[4],v1[5]), pk2(v1[6],v1[7]));
        }
        f32x16 accE = z16;
        accE = __builtin_amdgcn_mfma_f32_32x32x16_f16(aX0, bA0, accE, 0, 0, 0);
        accE = __builtin_amdgcn_mfma_f32_32x32x16_f16(aX1, bA1, accE, 0, 0, 0);
        const unsigned p01 = pk2(accE[0], accE[1]), p23 = pk2(accE[2], accE[3]);
        const unsigned p4  = dup_hi(pk2(accE[0], 0.f));   // row4 lives in hi half
        const f16x8 bE = hf ? mkfrag(0u, 0u, 0u, 0u) : mkfrag(p01, p23, p4, 0u);
        f32x16 s0 = z16, s1 = z16;
        s0 = __builtin_amdgcn_mfma_f32_32x32x16_f16(aWg0, bE, s0, 0, 0, 0);
        s1 = __builtin_amdgcn_mfma_f32_32x32x16_f16(aWg1, bE, s1, 0, 0, 0);
        #pragma unroll
        for (int i = 0; i < 16; ++i) { s0[i] = fmaxf(s0[i], 0.f); s1[i] = fmaxf(s1[i], 0.f); }
        cvt_tile(s0, o0, o1);
        cvt_tile(s1, o2, o3);
    };

    auto gru_mfma = [&](int hnum, f32x16& aR, f32x16& aZ, f32x16& aNi, f32x16& aNh) {
        const int tR = hnum, tZ = 2 + hnum, tN = 4 + hnum;
        aR = z16; aZ = z16; aNi = z16; aNh = z16;
        #define GSTEP(kt, BS, BH) \
            aR  = mm(aR,  (0 * 6 + tR) * 5 + kt, BS); \
            aR  = mm(aR,  (1 * 6 + tR) * 5 + kt, BH); \
            aZ  = mm(aZ,  (0 * 6 + tZ) * 5 + kt, BS); \
            aZ  = mm(aZ,  (1 * 6 + tZ) * 5 + kt, BH); \
            aNi = mm(aNi, (0 * 6 + tN) * 5 + kt, BS); \
            aNh = mm(aNh, (1 * 6 + tN) * 5 + kt, BH);
        GSTEP(0, bS0, bH0)
        GSTEP(1, bS1, bH1)
        GSTEP(2, bS2, bH2)
        GSTEP(3, bS3, bH3)
        #undef GSTEP
        aR  = mm(aR,  (0 * 6 + tR) * 5 + 4, bC);
        aZ  = mm(aZ,  (0 * 6 + tZ) * 5 + 4, bC);
        aNi = mm(aNi, (0 * 6 + tN) * 5 + 4, bC);
        aNh = mm(aNh, (1 * 6 + tN) * 5 + 4, bC);
    };
    auto act = [&](f32x16& hv, const f32x16& aR, const f32x16& aZ,
                   const f32x16& aNi, const f32x16& aNh, f16x8& nbe, f16x8& nbo) {
        #pragma unroll
        for (int i = 0; i < 16; ++i) {
            const float r = sigm(aR[i]);
            const float z = sigm(aZ[i]);
            const float n = tanhp(aNi[i] + r * aNh[i]);
            hv[i] = n + z * (hv[i] - n);
        }
        cvt_tile(hv, nbe, nbo);
    };

    // ---- prologue: S(0) + prefetch t=1 ----
    load_x(0); stage_x();
    load_adj(0); pack_adj();
    load_x(1);
    spath(bS0, bS1, bS2, bS3);
    load_adj(1);

    // ---- history, pipelined: iter t does GRU(t) and S-path(t+1) ----
    for (int t = 0; t < 49; ++t) {
        f32x16 aR0, aZ0, aNi0, aNh0, aR1, aZ1, aNi1, aNh1;
        f16x8 nb0, nb1, nb2, nb3, nS0, nS1, nS2, nS3;
        gru_mfma(0, aR0, aZ0, aNi0, aNh0);
        stage_x();                         // xL <- x(t+1)
        act(hC0, aR0, aZ0, aNi0, aNh0, nb0, nb1);
        pack_adj();                        // bA <- adj(t+1)
        const int tp = (t + 2 < 50) ? t + 2 : 49;   // clamp: keeps body branch-free
        load_adj(tp); load_x(tp);          // c <- adj(t+2), pfx <- x(t+2)
        spath(nS0, nS1, nS2, nS3);         // bS_next = S(t+1), overlaps GRU/act
        gru_mfma(1, aR1, aZ1, aNi1, aNh1);
        act(hC1, aR1, aZ1, aNi1, aNh1, nb2, nb3);
        bH0 = nb0; bH1 = nb1; bH2 = nb2; bH3 = nb3;
        bS0 = nS0; bS1 = nS1; bS2 = nS2; bS3 = nS3;
    }

    // ---- t = 49: last history GRU (bS = S(49), bA = adj(49), xL = x(49)) ----
    {
        f32x16 aR0, aZ0, aNi0, aNh0, aR1, aZ1, aNi1, aNh1;
        f16x8 nb0, nb1, nb2, nb3;
        gru_mfma(0, aR0, aZ0, aNi0, aNh0);
        act(hC0, aR0, aZ0, aNi0, aNh0, nb0, nb1);
        gru_mfma(1, aR1, aZ1, aNi1, aNh1);
        act(hC1, aR1, aZ1, aNi1, aNh1, nb2, nb3);
        bH0 = nb0; bH1 = nb1; bH2 = nb2; bH3 = nb3;
    }

    // ---- future: serial (decode(t) feeds x(t+1)); adj frags fixed at t=49 ----
    for (int fs = 0; fs < 10; ++fs) {
        spath(bS0, bS1, bS2, bS3);
        f32x16 aR0, aZ0, aNi0, aNh0, aR1, aZ1, aNi1, aNh1;
        f16x8 nb0, nb1, nb2, nb3;
        gru_mfma(0, aR0, aZ0, aNi0, aNh0);
        act(hC0, aR0, aZ0, aNi0, aNh0, nb0, nb1);
        gru_mfma(1, aR1, aZ1, aNi1, aNh1);
        act(hC1, aR1, aZ1, aNi1, aNh1, nb2, nb3);
        bH0 = nb0; bH1 = nb1; bH2 = nb2; bH3 = nb3;

        f32x16 d1 = z16;
        d1 = mm(d1, 60, bH0);
        d1 = mm(d1, 61, bH1);
        d1 = mm(d1, 62, bH2);
        d1 = mm(d1, 63, bH3);
        d1 = mm(d1, 64, bC);
        #pragma unroll
        for (int i = 0; i < 16; ++i) d1[i] = fmaxf(d1[i], 0.f);
        f16x8 bD0, bD1;
        cvt_tile(d1, bD0, bD1);
        f32x16 d2 = z16;
        d2 = mm(d2, 65, bD0);
        d2 = mm(d2, 66, bD1);
        d2 = mm(d2, 67, bC);
        if (hf == 0 && l31 < 23) {
            f32x4n o;
            o[0] = d2[0]; o[1] = d2[1]; o[2] = d2[2]; o[3] = d2[3];
            *(f32x4n*)(outb + fs * 92 + l31 * 4) = o;
            *(f32x4n*)(xL + l31 * 4) = o;     // feeds next step's X^
        }
    }
}

extern "C" void kernel_launch(void* const* d_in, const int* in_sizes, int n_in,
                              void* d_out, int out_size, void* d_ws, size_t ws_size,
                              hipStream_t stream) {
    (void)in_sizes; (void)n_in; (void)d_ws; (void)ws_size; (void)out_size;
    hipFuncSetAttribute((const void*)gwm_kernel,
                        hipFuncAttributeMaxDynamicSharedMemorySize, SMEM_BYTES);
    gwm_kernel<<<dim3(256), dim3(512), SMEM_BYTES, stream>>>(
        (const float*)d_in[0], (const float*)d_in[1], (const float*)d_in[2],
        (const float*)d_in[3], (const float*)d_in[4], (const float*)d_in[5],
        (const float*)d_in[6], (const float*)d_in[7], (const float*)d_in[8],
        (const float*)d_in[9], (const float*)d_in[10], (const float*)d_in[11],
        (float*)d_out);
}